// Round 8
// baseline (552.099 us; speedup 1.0000x reference)
//
#include <hip/hip_runtime.h>
#include <hip/hip_fp16.h>
#include <math.h>

#define F_IN  256
#define F_HID 64
#define F_OUT 40
#define HS2_LD 64   // fp16 row stride: 64*2B = one 128B line

typedef _Float16 h8 __attribute__((ext_vector_type(8)));
typedef float f4 __attribute__((ext_vector_type(4)));

// ---------------------------------------------------------------- deg histogram + weight prep (merged)
__global__ void k_degw(const int* __restrict__ dst, unsigned* __restrict__ degc, int E,
                       const float* __restrict__ W1, const float* __restrict__ W2,
                       __half* __restrict__ Wt, __half* __restrict__ W2t) {
    int i = blockIdx.x * 256 + threadIdx.x;
    if (i < E) {
        atomicAdd(&degc[dst[i]], 1u);
        return;
    }
    int j = i - E;
    if (j < 16384) {
        int k = j >> 6, n = j & 63;
        Wt[n * 256 + k] = __float2half(W1[j]);
    } else if (j < 20480) {
        int jj = j - 16384;
        int n = jj >> 6, k = jj & 63;
        W2t[n * 64 + k] = __float2half((n < F_OUT) ? W2[k * F_OUT + n] : 0.f);
    }
}

// ---------------------------------------------------------------- single-kernel scan (decoupled lookback)
// pdeg = (deg+8)&~7. Publishes agg (flag 1) then prefix (flag 3) in aggf[b];
// value in low 30 bits. Ticket-ordered blocks; 391 blocks all co-resident
// (>=512 slots) -> aggregates always publish -> no deadlock.
// Lookback is WAVE-PARALLEL: 64 flags per step instead of 1.
__global__ __launch_bounds__(256) void k_scan(const unsigned* __restrict__ degc,
                                              unsigned* __restrict__ aggf,
                                              unsigned* __restrict__ ticket,
                                              unsigned* __restrict__ rowptr,
                                              float* __restrict__ dinv,
                                              unsigned* __restrict__ cursor,
                                              float* __restrict__ colsum, int N) {
    __shared__ unsigned s[256];
    __shared__ unsigned sTick, sPfx, sTot;
    int tid = threadIdx.x;
    if (tid == 0) sTick = atomicAdd(ticket, 1u);
    if (blockIdx.x == 0 && tid < 64) colsum[tid] = 0.f;
    __syncthreads();
    unsigned b = sTick;
    int i = (int)b * 256 + tid;
    unsigned d = (i < N) ? degc[i] : 0u;
    unsigned v = (i < N) ? ((d + 8u) & ~7u) : 0u;
    s[tid] = v;
    __syncthreads();
    for (int off = 1; off < 256; off <<= 1) {
        unsigned t = (tid >= off) ? s[tid - off] : 0u;
        __syncthreads();
        s[tid] += t;
        __syncthreads();
    }
    unsigned incl = s[tid];
    if (tid == 255) {
        sTot = s[255];
        atomicExch(&aggf[b], s[255] | 0x40000000u);  // publish aggregate
    }
    __syncthreads();
    if (tid < 64) {  // wave 0: parallel lookback
        int lane = tid;
        unsigned run = 0;
        int base = (int)b - 1;  // lane l inspects index base - l (lane 0 = nearest)
        while (base >= 0) {
            int idx = base - lane;
            unsigned t = 0;
            if (idx >= 0) {
                do { t = atomicAdd(&aggf[idx], 0u); } while ((t >> 30) == 0u);
            }
            unsigned long long pmask = __ballot(idx >= 0 && (t >> 30) == 3u);
            if (pmask) {
                int L = __ffsll((unsigned long long)pmask) - 1;  // nearest prefix
                unsigned contrib = (lane <= L) ? (t & 0x3FFFFFFFu) : 0u;
                #pragma unroll
                for (int off = 32; off >= 1; off >>= 1) contrib += __shfl_xor(contrib, off, 64);
                run += contrib;
                break;
            } else {
                unsigned contrib = (idx >= 0) ? (t & 0x3FFFFFFFu) : 0u;
                #pragma unroll
                for (int off = 32; off >= 1; off >>= 1) contrib += __shfl_xor(contrib, off, 64);
                run += contrib;
                base -= 64;
            }
        }
        if (lane == 0) {
            sPfx = run;
            atomicExch(&aggf[b], (run + sTot) | 0xC0000000u);  // publish prefix
        }
    }
    __syncthreads();
    unsigned pfx = sPfx;
    if (i < N) {
        rowptr[i] = pfx + incl - v;
        dinv[i] = rsqrtf((float)d + 1.0f);  // +1 self loop
        cursor[i] = 0u;
        if (i == N - 1) rowptr[N] = pfx + incl;
    }
    if (i == 0) dinv[N] = 1.0f;  // sentinel
}

// ---------------------------------------------------------------- fill + pad, range-partitioned scatter
// SEPARATE kernel (R5 fusion with mm1 regressed: co-running x-stream evicted
// the L2-resident colp windows -> WRITE_SIZE 65 MB, 98 us). 8 ranges, window
// ~0.9 MB/XCD-L2; exclusive use of the machine keeps scatter writes coalescing
// in L2 (proven in R1: fillpad dropped out of top-5).
__global__ __launch_bounds__(256) void k_fillpad(const int* __restrict__ src, const int* __restrict__ dst,
                          const unsigned* __restrict__ degc,
                          const unsigned* __restrict__ rowptr, unsigned* __restrict__ cursor,
                          unsigned* __restrict__ colp, int E, int N) {
    int r  = blockIdx.x & 7;
    int sb = blockIdx.x >> 3;
    int S  = gridDim.x >> 3;          // blocks per range
    int lo = (int)(((long long)N * r) >> 3);
    int hi = (int)(((long long)N * (r + 1)) >> 3);
    int tid = threadIdx.x;
    int stride = S * 256;
    for (int t = sb * 256 + tid; t < E; t += stride) {
        int d = dst[t];
        if (d >= lo && d < hi) {
            unsigned p = atomicAdd(&cursor[d], 1u);
            colp[rowptr[d] + p] = (unsigned)src[t];
        }
    }
    int npad = (hi - lo) * 8;
    for (int z = sb * 256 + tid; z < npad; z += stride) {
        int i = lo + (z >> 3), j = z & 7;
        unsigned d = degc[i];
        unsigned slot = d + (unsigned)j;
        if (slot < ((d + 8u) & ~7u))
            colp[rowptr[i] + slot] = (j == 0) ? (unsigned)i : (unsigned)N;
    }
}

// ---------------------------------------------------------------- hs1 = (x @ W1) * dinv, fp16, MFMA
// LDS-free: each wave owns 16 nodes x all 64 cols. A-frag loads straight from
// global x; B-frags from 32KB L1-resident Wt. No barriers, no bank conflicts.
__global__ __launch_bounds__(256) void k_mm1(const float* __restrict__ x,
                                             const __half* __restrict__ Wth,
                                             const float* __restrict__ dinv,
                                             __half* __restrict__ hs1o, int N) {
    const _Float16* Wt = (const _Float16*)Wth;
    _Float16* hs1 = (_Float16*)hs1o;
    int tid = threadIdx.x;
    int lane = tid & 63;
    int wv = tid >> 6;
    int m15 = lane & 15;
    int q = lane >> 4;
    int node0 = blockIdx.x * 64 + wv * 16;
    int arow = node0 + m15;
    bool ok = (arow < N);
    const float* xr = x + (size_t)arow * F_IN + q * 8;

    f4 acc[4];
    #pragma unroll
    for (int nt = 0; nt < 4; ++nt) acc[nt] = (f4){0.f, 0.f, 0.f, 0.f};

    #pragma unroll
    for (int kt = 0; kt < 8; ++kt) {
        float4 v0, v1;
        if (ok) {
            v0 = *(const float4*)(xr + kt * 32);
            v1 = *(const float4*)(xr + kt * 32 + 4);
        } else {
            v0 = make_float4(0.f, 0.f, 0.f, 0.f);
            v1 = v0;
        }
        h8 a = { (_Float16)v0.x, (_Float16)v0.y, (_Float16)v0.z, (_Float16)v0.w,
                 (_Float16)v1.x, (_Float16)v1.y, (_Float16)v1.z, (_Float16)v1.w };
        #pragma unroll
        for (int nt = 0; nt < 4; ++nt) {
            h8 b = *(const h8*)(Wt + (nt * 16 + m15) * 256 + kt * 32 + q * 8);
            acc[nt] = __builtin_amdgcn_mfma_f32_16x16x32_f16(a, b, acc[nt], 0, 0, 0);
        }
    }

    #pragma unroll
    for (int nt = 0; nt < 4; ++nt) {
        #pragma unroll
        for (int rr = 0; rr < 4; ++rr) {
            int node = node0 + q * 4 + rr;
            if (node <= N) {
                float din = (node < N) ? dinv[node] : 1.0f;
                hs1[(size_t)node * F_HID + nt * 16 + m15] = (_Float16)(acc[nt][rr] * din);
            }
        }
    }
}

// ---------------------------------------------------------------- gather layer 1
// 4 masked streams per wave in ONE basic block, colp indices prefetched one
// iteration ahead. __launch_bounds__(256,8) pins VGPR <= 64: R7 proved TLP
// (8 waves/SIMD) is the controlling resource for this latency-bound gather —
// 8 streams @ 124 VGPR halved occupancy and cost +31 us.
__global__ __launch_bounds__(256, 8) void k_agg1(const unsigned* __restrict__ rowptr,
                                              const unsigned* __restrict__ colp,
                                              const float* __restrict__ dinv,
                                              const __half* __restrict__ hs1o,
                                              const float* __restrict__ bias1,
                                              __half* __restrict__ agg1o, int N) {
    const _Float16* hp = (const _Float16*)hs1o;
    _Float16* agg1h = (_Float16*)agg1o;
    int lane = threadIdx.x & 63;
    int w = blockIdx.x * 4 + (threadIdx.x >> 6);
    int n0 = 4 * w;
    if (n0 >= N) return;
    int g = lane >> 3, c = lane & 7;

    float acc[4][8];
    #pragma unroll
    for (int s = 0; s < 4; ++s)
        #pragma unroll
        for (int j = 0; j < 8; ++j) acc[s][j] = 0.f;

    unsigned e[4], en[4], idx[4];
    #pragma unroll
    for (int s = 0; s < 4; ++s) {
        int nd = n0 + s;
        if (nd < N) { e[s] = rowptr[nd]; en[s] = rowptr[nd + 1]; }
        else        { e[s] = 0; en[s] = 0; }
    }
    #pragma unroll
    for (int s = 0; s < 4; ++s) {
        unsigned ec = (e[s] < en[s]) ? e[s] : (en[s] - 8u);
        ec = (ec > e[s]) ? e[s] : ec;   // inactive stream (en=0): underflow -> use e
        idx[s] = colp[ec + g];
    }

    while (e[0] < en[0] || e[1] < en[1] || e[2] < en[2] || e[3] < en[3]) {
        float msk[4];
        h8 v[4];
        #pragma unroll
        for (int s = 0; s < 4; ++s) msk[s] = (e[s] < en[s]) ? 1.f : 0.f;
        #pragma unroll
        for (int s = 0; s < 4; ++s) v[s] = *(const h8*)(hp + (size_t)idx[s] * F_HID + c * 8);
        #pragma unroll
        for (int s = 0; s < 4; ++s) {
            e[s] += 8;
            unsigned ec = (e[s] < en[s]) ? e[s] : (en[s] - 8u);
            ec = (ec > e[s]) ? e[s] : ec;
            idx[s] = colp[ec + g];      // prefetch next chunk's index
        }
        #pragma unroll
        for (int s = 0; s < 4; ++s)
            #pragma unroll
            for (int j = 0; j < 8; ++j) acc[s][j] += (float)v[s][j] * msk[s];
    }

    #pragma unroll
    for (int off = 8; off <= 32; off <<= 1)
        #pragma unroll
        for (int s = 0; s < 4; ++s)
            #pragma unroll
            for (int j = 0; j < 8; ++j) acc[s][j] += __shfl_xor(acc[s][j], off, 64);

    if (g == 0) {
        float bv[8];
        *(float4*)&bv[0] = *(const float4*)(bias1 + c * 8);
        *(float4*)&bv[4] = *(const float4*)(bias1 + c * 8 + 4);
        #pragma unroll
        for (int s = 0; s < 4; ++s) {
            int nd = n0 + s;
            if (nd < N) {
                float din = dinv[nd];
                h8 ho;
                #pragma unroll
                for (int j = 0; j < 8; ++j) ho[j] = (_Float16)fmaxf(acc[s][j] * din + bv[j], 0.f);
                *(h8*)(agg1h + (size_t)nd * F_HID + c * 8) = ho;
            }
        }
    }
}

// ---------------------------------------------------------------- hs2 = (agg1 @ W2) * dinv, fp16, MFMA
// SEPARATE from agg1 (R6 fusion measured +6 us vs R3's split: fewer blocks +
// in-block barrier outweighed the saved 25 MB round-trip).
#define AS 72   // 144 B LDS row stride: 16B-aligned, bank-stride 4 (2-way, free)
__global__ __launch_bounds__(256) void k_mm2(const __half* __restrict__ agg1o,
                                             const __half* __restrict__ W2th,
                                             const float* __restrict__ dinv,
                                             __half* __restrict__ hs2o, int N) {
    __shared__ _Float16 sA[64 * AS];  // 9216 B
    const _Float16* agg1h = (const _Float16*)agg1o;
    const _Float16* W2t = (const _Float16*)W2th;
    _Float16* hs2 = (_Float16*)hs2o;
    int tid = threadIdx.x;
    int lane = tid & 63;
    int wv = tid >> 6;
    int m15 = lane & 15;
    int q = lane >> 4;
    int nbase = blockIdx.x * 64;

    h8 bf[2];
    #pragma unroll
    for (int kt = 0; kt < 2; ++kt)
        bf[kt] = *(const h8*)(W2t + (wv * 16 + m15) * 64 + kt * 32 + q * 8);

    #pragma unroll
    for (int p = 0; p < 2; ++p) {
        int idx = p * 256 + tid;
        int row = idx >> 3;
        int c8  = idx & 7;
        int node = nbase + row;
        h8 v;
        if (node < N) v = *(const h8*)(agg1h + (size_t)node * F_HID + c8 * 8);
        else          v = (h8){0, 0, 0, 0, 0, 0, 0, 0};
        *(h8*)&sA[row * AS + c8 * 8] = v;
    }
    __syncthreads();

    f4 acc[4];
    #pragma unroll
    for (int mt = 0; mt < 4; ++mt) acc[mt] = (f4){0.f, 0.f, 0.f, 0.f};
    #pragma unroll
    for (int kt = 0; kt < 2; ++kt) {
        #pragma unroll
        for (int mt = 0; mt < 4; ++mt) {
            h8 a = *(const h8*)&sA[(mt * 16 + m15) * AS + kt * 32 + q * 8];
            acc[mt] = __builtin_amdgcn_mfma_f32_16x16x32_f16(a, bf[kt], acc[mt], 0, 0, 0);
        }
    }

    #pragma unroll
    for (int mt = 0; mt < 4; ++mt) {
        #pragma unroll
        for (int r = 0; r < 4; ++r) {
            int node = nbase + mt * 16 + q * 4 + r;
            if (node <= N) {
                float din = (node < N) ? dinv[node] : 1.0f;
                hs2[(size_t)node * HS2_LD + wv * 16 + m15] = (_Float16)(acc[mt][r] * din);
            }
        }
    }
}

// ---------------------------------------------------------------- gather layer 2 (masked pipeline, 4 streams)
__global__ __launch_bounds__(256, 8) void k_agg2(const unsigned* __restrict__ rowptr,
                                              const unsigned* __restrict__ colp,
                                              const float* __restrict__ dinv,
                                              const __half* __restrict__ hs2o,
                                              float* __restrict__ out,
                                              float* __restrict__ colsum, int N) {
    __shared__ float part[4][8][8];
    const _Float16* hp = (const _Float16*)hs2o;
    int lane = threadIdx.x & 63;
    int wv = threadIdx.x >> 6;
    int g = lane >> 3, c = lane & 7;
    int nwaves = gridDim.x * 4;
    float csum[8];
    #pragma unroll
    for (int j = 0; j < 8; ++j) csum[j] = 0.f;

    for (int w = blockIdx.x * 4 + wv; 4 * w < N; w += nwaves) {
        int n0 = 4 * w;
        float acc[4][8];
        #pragma unroll
        for (int s = 0; s < 4; ++s)
            #pragma unroll
            for (int j = 0; j < 8; ++j) acc[s][j] = 0.f;

        unsigned e[4], en[4], idx[4];
        #pragma unroll
        for (int s = 0; s < 4; ++s) {
            int nd = n0 + s;
            if (nd < N) { e[s] = rowptr[nd]; en[s] = rowptr[nd + 1]; }
            else        { e[s] = 0; en[s] = 0; }
        }
        #pragma unroll
        for (int s = 0; s < 4; ++s) {
            unsigned ec = (e[s] < en[s]) ? e[s] : (en[s] - 8u);
            ec = (ec > e[s]) ? e[s] : ec;
            idx[s] = colp[ec + g];
        }

        while (e[0] < en[0] || e[1] < en[1] || e[2] < en[2] || e[3] < en[3]) {
            float msk[4];
            h8 v[4];
            #pragma unroll
            for (int s = 0; s < 4; ++s) msk[s] = (e[s] < en[s]) ? 1.f : 0.f;
            #pragma unroll
            for (int s = 0; s < 4; ++s) v[s] = *(const h8*)(hp + (size_t)idx[s] * HS2_LD + c * 8);
            #pragma unroll
            for (int s = 0; s < 4; ++s) {
                e[s] += 8;
                unsigned ec = (e[s] < en[s]) ? e[s] : (en[s] - 8u);
                ec = (ec > e[s]) ? e[s] : ec;
                idx[s] = colp[ec + g];
            }
            #pragma unroll
            for (int s = 0; s < 4; ++s)
                #pragma unroll
                for (int j = 0; j < 8; ++j) acc[s][j] += (float)v[s][j] * msk[s];
        }

        #pragma unroll
        for (int off = 8; off <= 32; off <<= 1)
            #pragma unroll
            for (int s = 0; s < 4; ++s)
                #pragma unroll
                for (int j = 0; j < 8; ++j) acc[s][j] += __shfl_xor(acc[s][j], off, 64);

        if (g == 0) {
            #pragma unroll
            for (int s = 0; s < 4; ++s) {
                int nd = n0 + s;
                if (nd < N) {
                    float din = dinv[nd];
                    #pragma unroll
                    for (int j = 0; j < 8; ++j) { acc[s][j] *= din; csum[j] += acc[s][j]; }
                    if (c < 5) {
                        *(float4*)(out + (size_t)nd * F_OUT + c * 8) =
                            make_float4(acc[s][0], acc[s][1], acc[s][2], acc[s][3]);
                        *(float4*)(out + (size_t)nd * F_OUT + c * 8 + 4) =
                            make_float4(acc[s][4], acc[s][5], acc[s][6], acc[s][7]);
                    }
                }
            }
        }
    }

    if (g == 0) {
        #pragma unroll
        for (int j = 0; j < 8; ++j) part[wv][c][j] = csum[j];
    }
    __syncthreads();
    int tid = threadIdx.x;
    if (tid < F_OUT) {
        int cc = tid >> 3, jj = tid & 7;
        float s = part[0][cc][jj] + part[1][cc][jj] + part[2][cc][jj] + part[3][cc][jj];
        atomicAdd(&colsum[tid], s);
    }
}

// ---------------------------------------------------------------- PairNorm-SI + log_softmax (float4)
__global__ __launch_bounds__(128) void k_final(float* __restrict__ out,
                                               const float* __restrict__ colsum, int N) {
    __shared__ float sMean[F_OUT];
    if (threadIdx.x < F_OUT) sMean[threadIdx.x] = colsum[threadIdx.x] * (1.0f / (float)N);
    __syncthreads();
    int n = blockIdx.x * blockDim.x + threadIdx.x;
    if (n >= N) return;
    float* row = out + (size_t)n * F_OUT;
    float4 vr[10];
    float ss = 0.f;
    #pragma unroll
    for (int b = 0; b < 10; ++b) {
        float4 t = *(const float4*)(row + b * 4);
        t.x -= sMean[b * 4 + 0]; t.y -= sMean[b * 4 + 1];
        t.z -= sMean[b * 4 + 2]; t.w -= sMean[b * 4 + 3];
        vr[b] = t;
        ss += t.x * t.x + t.y * t.y + t.z * t.z + t.w * t.w;
    }
    float scale = 1.0f / sqrtf(ss + 1e-6f);
    float m = -1e30f;
    #pragma unroll
    for (int b = 0; b < 10; ++b) {
        vr[b].x *= scale; vr[b].y *= scale; vr[b].z *= scale; vr[b].w *= scale;
        m = fmaxf(m, fmaxf(fmaxf(vr[b].x, vr[b].y), fmaxf(vr[b].z, vr[b].w)));
    }
    float sum = 0.f;
    #pragma unroll
    for (int b = 0; b < 10; ++b)
        sum += expf(vr[b].x - m) + expf(vr[b].y - m) + expf(vr[b].z - m) + expf(vr[b].w - m);
    float mlse = m + logf(sum);
    #pragma unroll
    for (int b = 0; b < 10; ++b) {
        float4 t = vr[b];
        t.x -= mlse; t.y -= mlse; t.z -= mlse; t.w -= mlse;
        *(float4*)(row + b * 4) = t;
    }
}

extern "C" void kernel_launch(void* const* d_in, const int* in_sizes, int n_in,
                              void* d_out, int out_size, void* d_ws, size_t ws_size,
                              hipStream_t stream) {
    const float* x  = (const float*)d_in[0];
    const int*   ei = (const int*)d_in[1];   // int32 per harness (verified R1)
    const float* W1 = (const float*)d_in[2];
    const float* b1 = (const float*)d_in[3];
    const float* W2 = (const float*)d_in[4];
    // b2 unused: cancels under PairNorm mean subtraction.
    float* out = (float*)d_out;

    int N = in_sizes[0] / F_IN;
    int E = in_sizes[1] / 2;
    const int* src = ei;
    const int* dst = ei + E;

    // byte layout with 128B alignment per region.
    // memset zone: degc + aggf + ticket (must precede everything else).
    char* p = (char*)d_ws;
    auto alloc = [&](size_t bytes) { char* r = p; p += (bytes + 127) & ~(size_t)127; return r; };
    unsigned* degc   = (unsigned*)alloc((size_t)N * 4);
    unsigned* aggf   = (unsigned*)alloc(512 * 4);
    unsigned* ticket = (unsigned*)alloc(4);
    char* zend = p;  // end of memset zone
    unsigned* cursor = (unsigned*)alloc((size_t)N * 4);
    float*    colsum = (float*)   alloc(64 * 4);
    unsigned* rowptr = (unsigned*)alloc((size_t)(N + 1) * 4);
    unsigned* colp   = (unsigned*)alloc((size_t)(E + 8 * N + 8) * 4);
    float*    dinv   = (float*)   alloc((size_t)(N + 1) * 4);
    __half*   agg1h  = (__half*)  alloc((size_t)64 * (N + 1) * 2);
    __half*   hs1    = (__half*)  alloc((size_t)64 * (N + 1) * 2);
    __half*   hs2    = (__half*)  alloc((size_t)64 * (N + 1) * 2);
    __half*   Wt     = (__half*)  alloc((size_t)16384 * 2);
    __half*   W2t    = (__half*)  alloc((size_t)4096 * 2);

    hipMemsetAsync(d_ws, 0, (size_t)(zend - (char*)d_ws), stream);

    int nA = (N + 255) / 256;  // 391 for N=100000 (<512 aggf slots)
    k_degw<<<(E + 20480 + 255) / 256, 256, 0, stream>>>(dst, degc, E, W1, W2, Wt, W2t);
    k_scan<<<nA, 256, 0, stream>>>(degc, aggf, ticket, rowptr, dinv, cursor, colsum, N);
    k_fillpad<<<2048, 256, 0, stream>>>(src, dst, degc, rowptr, cursor, colp, E, N);
    k_mm1<<<(N + 63) / 64, 256, 0, stream>>>(x, Wt, dinv, hs1, N);
    int nodes4 = (N + 3) / 4;                       // waves needed (4 nodes/wave)
    k_agg1<<<(nodes4 + 3) / 4, 256, 0, stream>>>(rowptr, colp, dinv, hs1, b1, agg1h, N);
    k_mm2<<<(N + 64) / 64, 256, 0, stream>>>(agg1h, W2t, dinv, hs2, N);
    k_agg2<<<2048, 256, 0, stream>>>(rowptr, colp, dinv, hs2, out, colsum, N);
    k_final<<<(N + 127) / 128, 128, 0, stream>>>(out, colsum, N);
}

// Round 9
// 392.513 us; speedup vs baseline: 1.4066x; 1.4066x over previous
//
#include <hip/hip_runtime.h>
#include <hip/hip_fp16.h>
#include <math.h>

#define F_IN  256
#define F_HID 64
#define F_OUT 40
#define HS2_LD 64   // fp16 row stride: 64*2B = one 128B line

typedef _Float16 h8 __attribute__((ext_vector_type(8)));
typedef _Float16 h4 __attribute__((ext_vector_type(4)));
typedef float f4 __attribute__((ext_vector_type(4)));

// ---------------------------------------------------------------- deg histogram + weight prep (merged)
__global__ void k_degw(const int* __restrict__ dst, unsigned* __restrict__ degc, int E,
                       const float* __restrict__ W1, const float* __restrict__ W2,
                       __half* __restrict__ Wt, __half* __restrict__ W2t) {
    int i = blockIdx.x * 256 + threadIdx.x;
    if (i < E) {
        atomicAdd(&degc[dst[i]], 1u);
        return;
    }
    int j = i - E;
    if (j < 16384) {
        int k = j >> 6, n = j & 63;
        Wt[n * 256 + k] = __float2half(W1[j]);
    } else if (j < 20480) {
        int jj = j - 16384;
        int n = jj >> 6, k = jj & 63;
        W2t[n * 64 + k] = __float2half((n < F_OUT) ? W2[k * F_OUT + n] : 0.f);
    }
}

// ---------------------------------------------------------------- single-kernel scan (decoupled lookback)
// pdeg = (deg+8)&~7. Publishes agg (flag 1) then prefix (flag 3) in aggf[b];
// value in low 30 bits. Ticket-ordered blocks; 391 blocks all co-resident
// (>=512 slots) -> aggregates always publish -> no deadlock.
// Lookback is WAVE-PARALLEL: 64 flags per step instead of 1.
__global__ __launch_bounds__(256) void k_scan(const unsigned* __restrict__ degc,
                                              unsigned* __restrict__ aggf,
                                              unsigned* __restrict__ ticket,
                                              unsigned* __restrict__ rowptr,
                                              float* __restrict__ dinv,
                                              unsigned* __restrict__ cursor,
                                              float* __restrict__ colsum, int N) {
    __shared__ unsigned s[256];
    __shared__ unsigned sTick, sPfx, sTot;
    int tid = threadIdx.x;
    if (tid == 0) sTick = atomicAdd(ticket, 1u);
    if (blockIdx.x == 0 && tid < 64) colsum[tid] = 0.f;
    __syncthreads();
    unsigned b = sTick;
    int i = (int)b * 256 + tid;
    unsigned d = (i < N) ? degc[i] : 0u;
    unsigned v = (i < N) ? ((d + 8u) & ~7u) : 0u;
    s[tid] = v;
    __syncthreads();
    for (int off = 1; off < 256; off <<= 1) {
        unsigned t = (tid >= off) ? s[tid - off] : 0u;
        __syncthreads();
        s[tid] += t;
        __syncthreads();
    }
    unsigned incl = s[tid];
    if (tid == 255) {
        sTot = s[255];
        atomicExch(&aggf[b], s[255] | 0x40000000u);  // publish aggregate
    }
    __syncthreads();
    if (tid < 64) {  // wave 0: parallel lookback
        int lane = tid;
        unsigned run = 0;
        int base = (int)b - 1;  // lane l inspects index base - l (lane 0 = nearest)
        while (base >= 0) {
            int idx = base - lane;
            unsigned t = 0;
            if (idx >= 0) {
                do { t = atomicAdd(&aggf[idx], 0u); } while ((t >> 30) == 0u);
            }
            unsigned long long pmask = __ballot(idx >= 0 && (t >> 30) == 3u);
            if (pmask) {
                int L = __ffsll((unsigned long long)pmask) - 1;  // nearest prefix
                unsigned contrib = (lane <= L) ? (t & 0x3FFFFFFFu) : 0u;
                #pragma unroll
                for (int off = 32; off >= 1; off >>= 1) contrib += __shfl_xor(contrib, off, 64);
                run += contrib;
                break;
            } else {
                unsigned contrib = (idx >= 0) ? (t & 0x3FFFFFFFu) : 0u;
                #pragma unroll
                for (int off = 32; off >= 1; off >>= 1) contrib += __shfl_xor(contrib, off, 64);
                run += contrib;
                base -= 64;
            }
        }
        if (lane == 0) {
            sPfx = run;
            atomicExch(&aggf[b], (run + sTot) | 0xC0000000u);  // publish prefix
        }
    }
    __syncthreads();
    unsigned pfx = sPfx;
    if (i < N) {
        rowptr[i] = pfx + incl - v;
        dinv[i] = rsqrtf((float)d + 1.0f);  // +1 self loop
        cursor[i] = 0u;
        if (i == N - 1) rowptr[N] = pfx + incl;
    }
    if (i == 0) dinv[N] = 1.0f;  // sentinel
}

// ---------------------------------------------------------------- fill + pad, range-partitioned scatter
// SEPARATE kernel (R5: fusing with mm1 evicted the L2-resident colp windows ->
// WRITE_SIZE 65 MB, 98 us). 8 ranges -> ~0.9 MB window per XCD L2; exclusive
// machine use keeps 4B scatter writes coalescing in L2 (R1: out of top-5).
__global__ __launch_bounds__(256) void k_fillpad(const int* __restrict__ src, const int* __restrict__ dst,
                          const unsigned* __restrict__ degc,
                          const unsigned* __restrict__ rowptr, unsigned* __restrict__ cursor,
                          unsigned* __restrict__ colp, int E, int N) {
    int r  = blockIdx.x & 7;
    int sb = blockIdx.x >> 3;
    int S  = gridDim.x >> 3;          // blocks per range
    int lo = (int)(((long long)N * r) >> 3);
    int hi = (int)(((long long)N * (r + 1)) >> 3);
    int tid = threadIdx.x;
    int stride = S * 256;
    for (int t = sb * 256 + tid; t < E; t += stride) {
        int d = dst[t];
        if (d >= lo && d < hi) {
            unsigned p = atomicAdd(&cursor[d], 1u);
            colp[rowptr[d] + p] = (unsigned)src[t];
        }
    }
    int npad = (hi - lo) * 8;
    for (int z = sb * 256 + tid; z < npad; z += stride) {
        int i = lo + (z >> 3), j = z & 7;
        unsigned d = degc[i];
        unsigned slot = d + (unsigned)j;
        if (slot < ((d + 8u) & ~7u))
            colp[rowptr[i] + slot] = (j == 0) ? (unsigned)i : (unsigned)N;
    }
}

// ---------------------------------------------------------------- hs1 = (x @ W1) * dinv, fp16, MFMA
// LDS-free: each wave owns 16 nodes x all 64 cols. A-frag loads straight from
// global x; B-frags from 32KB L1-resident Wt. No barriers, no bank conflicts.
__global__ __launch_bounds__(256) void k_mm1(const float* __restrict__ x,
                                             const __half* __restrict__ Wth,
                                             const float* __restrict__ dinv,
                                             __half* __restrict__ hs1o, int N) {
    const _Float16* Wt = (const _Float16*)Wth;
    _Float16* hs1 = (_Float16*)hs1o;
    int tid = threadIdx.x;
    int lane = tid & 63;
    int wv = tid >> 6;
    int m15 = lane & 15;
    int q = lane >> 4;
    int node0 = blockIdx.x * 64 + wv * 16;
    int arow = node0 + m15;
    bool ok = (arow < N);
    const float* xr = x + (size_t)arow * F_IN + q * 8;

    f4 acc[4];
    #pragma unroll
    for (int nt = 0; nt < 4; ++nt) acc[nt] = (f4){0.f, 0.f, 0.f, 0.f};

    #pragma unroll
    for (int kt = 0; kt < 8; ++kt) {
        float4 v0, v1;
        if (ok) {
            v0 = *(const float4*)(xr + kt * 32);
            v1 = *(const float4*)(xr + kt * 32 + 4);
        } else {
            v0 = make_float4(0.f, 0.f, 0.f, 0.f);
            v1 = v0;
        }
        h8 a = { (_Float16)v0.x, (_Float16)v0.y, (_Float16)v0.z, (_Float16)v0.w,
                 (_Float16)v1.x, (_Float16)v1.y, (_Float16)v1.z, (_Float16)v1.w };
        #pragma unroll
        for (int nt = 0; nt < 4; ++nt) {
            h8 b = *(const h8*)(Wt + (nt * 16 + m15) * 256 + kt * 32 + q * 8);
            acc[nt] = __builtin_amdgcn_mfma_f32_16x16x32_f16(a, b, acc[nt], 0, 0, 0);
        }
    }

    #pragma unroll
    for (int nt = 0; nt < 4; ++nt) {
        #pragma unroll
        for (int rr = 0; rr < 4; ++rr) {
            int node = node0 + q * 4 + rr;
            if (node <= N) {
                float din = (node < N) ? dinv[node] : 1.0f;
                hs1[(size_t)node * F_HID + nt * 16 + m15] = (_Float16)(acc[nt][rr] * din);
            }
        }
    }
}

// ---------------------------------------------------------------- gather layer 1
// 4 masked streams per wave in ONE basic block (per-stream `if` bodies
// serialize the chains — R2 lesson); colp indices prefetched one iteration
// ahead. NO launch_bounds occupancy pin: compiler lands at ~56 VGPR = 8
// waves/SIMD naturally; forcing (256,8) in R8 drove VGPR to 32 and spilled
// (280 MB scratch writes, 141 us). Do not re-add.
__global__ __launch_bounds__(256) void k_agg1(const unsigned* __restrict__ rowptr,
                                              const unsigned* __restrict__ colp,
                                              const float* __restrict__ dinv,
                                              const __half* __restrict__ hs1o,
                                              const float* __restrict__ bias1,
                                              __half* __restrict__ agg1o, int N) {
    const _Float16* hp = (const _Float16*)hs1o;
    _Float16* agg1h = (_Float16*)agg1o;
    int lane = threadIdx.x & 63;
    int w = blockIdx.x * 4 + (threadIdx.x >> 6);
    int n0 = 4 * w;
    if (n0 >= N) return;
    int g = lane >> 3, c = lane & 7;

    float acc[4][8];
    #pragma unroll
    for (int s = 0; s < 4; ++s)
        #pragma unroll
        for (int j = 0; j < 8; ++j) acc[s][j] = 0.f;

    unsigned e[4], en[4], idx[4];
    #pragma unroll
    for (int s = 0; s < 4; ++s) {
        int nd = n0 + s;
        if (nd < N) { e[s] = rowptr[nd]; en[s] = rowptr[nd + 1]; }
        else        { e[s] = 0; en[s] = 0; }
    }
    #pragma unroll
    for (int s = 0; s < 4; ++s) {
        unsigned ec = (e[s] < en[s]) ? e[s] : (en[s] - 8u);
        ec = (ec > e[s]) ? e[s] : ec;   // inactive stream (en=0): underflow -> use e
        idx[s] = colp[ec + g];
    }

    while (e[0] < en[0] || e[1] < en[1] || e[2] < en[2] || e[3] < en[3]) {
        float msk[4];
        h8 v[4];
        #pragma unroll
        for (int s = 0; s < 4; ++s) msk[s] = (e[s] < en[s]) ? 1.f : 0.f;
        #pragma unroll
        for (int s = 0; s < 4; ++s) v[s] = *(const h8*)(hp + (size_t)idx[s] * F_HID + c * 8);
        #pragma unroll
        for (int s = 0; s < 4; ++s) {
            e[s] += 8;
            unsigned ec = (e[s] < en[s]) ? e[s] : (en[s] - 8u);
            ec = (ec > e[s]) ? e[s] : ec;
            idx[s] = colp[ec + g];      // prefetch next chunk's index
        }
        #pragma unroll
        for (int s = 0; s < 4; ++s)
            #pragma unroll
            for (int j = 0; j < 8; ++j) acc[s][j] += (float)v[s][j] * msk[s];
    }

    #pragma unroll
    for (int off = 8; off <= 32; off <<= 1)
        #pragma unroll
        for (int s = 0; s < 4; ++s)
            #pragma unroll
            for (int j = 0; j < 8; ++j) acc[s][j] += __shfl_xor(acc[s][j], off, 64);

    if (g == 0) {
        float bv[8];
        *(float4*)&bv[0] = *(const float4*)(bias1 + c * 8);
        *(float4*)&bv[4] = *(const float4*)(bias1 + c * 8 + 4);
        #pragma unroll
        for (int s = 0; s < 4; ++s) {
            int nd = n0 + s;
            if (nd < N) {
                float din = dinv[nd];
                h8 ho;
                #pragma unroll
                for (int j = 0; j < 8; ++j) ho[j] = (_Float16)fmaxf(acc[s][j] * din + bv[j], 0.f);
                *(h8*)(agg1h + (size_t)nd * F_HID + c * 8) = ho;
            }
        }
    }
}

// ---------------------------------------------------------------- hs2 = (agg1 @ W2) * dinv, fp16, MFMA
// SEPARATE from agg1 (R6 fusion measured +6 us vs split: fewer blocks +
// in-block barrier outweighed the saved 25 MB round-trip).
#define AS 72   // 144 B LDS row stride: 16B-aligned, bank-stride 4 (2-way, free)
__global__ __launch_bounds__(256) void k_mm2(const __half* __restrict__ agg1o,
                                             const __half* __restrict__ W2th,
                                             const float* __restrict__ dinv,
                                             __half* __restrict__ hs2o, int N) {
    __shared__ _Float16 sA[64 * AS];  // 9216 B
    const _Float16* agg1h = (const _Float16*)agg1o;
    const _Float16* W2t = (const _Float16*)W2th;
    _Float16* hs2 = (_Float16*)hs2o;
    int tid = threadIdx.x;
    int lane = tid & 63;
    int wv = tid >> 6;
    int m15 = lane & 15;
    int q = lane >> 4;
    int nbase = blockIdx.x * 64;

    h8 bf[2];
    #pragma unroll
    for (int kt = 0; kt < 2; ++kt)
        bf[kt] = *(const h8*)(W2t + (wv * 16 + m15) * 64 + kt * 32 + q * 8);

    #pragma unroll
    for (int p = 0; p < 2; ++p) {
        int idx = p * 256 + tid;
        int row = idx >> 3;
        int c8  = idx & 7;
        int node = nbase + row;
        h8 v;
        if (node < N) v = *(const h8*)(agg1h + (size_t)node * F_HID + c8 * 8);
        else          v = (h8){0, 0, 0, 0, 0, 0, 0, 0};
        *(h8*)&sA[row * AS + c8 * 8] = v;
    }
    __syncthreads();

    f4 acc[4];
    #pragma unroll
    for (int mt = 0; mt < 4; ++mt) acc[mt] = (f4){0.f, 0.f, 0.f, 0.f};
    #pragma unroll
    for (int kt = 0; kt < 2; ++kt) {
        #pragma unroll
        for (int mt = 0; mt < 4; ++mt) {
            h8 a = *(const h8*)&sA[(mt * 16 + m15) * AS + kt * 32 + q * 8];
            acc[mt] = __builtin_amdgcn_mfma_f32_16x16x32_f16(a, bf[kt], acc[mt], 0, 0, 0);
        }
    }

    #pragma unroll
    for (int mt = 0; mt < 4; ++mt) {
        #pragma unroll
        for (int r = 0; r < 4; ++r) {
            int node = nbase + mt * 16 + q * 4 + r;
            if (node <= N) {
                float din = (node < N) ? dinv[node] : 1.0f;
                hs2[(size_t)node * HS2_LD + wv * 16 + m15] = (_Float16)(acc[mt][r] * din);
            }
        }
    }
}

// ---------------------------------------------------------------- gather layer 2 (masked pipeline, 4 streams)
// Same structure as k_agg1; grid-stride over 2048 blocks. No occupancy pin
// (R8 spill lesson).
__global__ __launch_bounds__(256) void k_agg2(const unsigned* __restrict__ rowptr,
                                              const unsigned* __restrict__ colp,
                                              const float* __restrict__ dinv,
                                              const __half* __restrict__ hs2o,
                                              float* __restrict__ out,
                                              float* __restrict__ colsum, int N) {
    __shared__ float part[4][8][8];
    const _Float16* hp = (const _Float16*)hs2o;
    int lane = threadIdx.x & 63;
    int wv = threadIdx.x >> 6;
    int g = lane >> 3, c = lane & 7;
    int nwaves = gridDim.x * 4;
    float csum[8];
    #pragma unroll
    for (int j = 0; j < 8; ++j) csum[j] = 0.f;

    for (int w = blockIdx.x * 4 + wv; 4 * w < N; w += nwaves) {
        int n0 = 4 * w;
        float acc[4][8];
        #pragma unroll
        for (int s = 0; s < 4; ++s)
            #pragma unroll
            for (int j = 0; j < 8; ++j) acc[s][j] = 0.f;

        unsigned e[4], en[4], idx[4];
        #pragma unroll
        for (int s = 0; s < 4; ++s) {
            int nd = n0 + s;
            if (nd < N) { e[s] = rowptr[nd]; en[s] = rowptr[nd + 1]; }
            else        { e[s] = 0; en[s] = 0; }
        }
        #pragma unroll
        for (int s = 0; s < 4; ++s) {
            unsigned ec = (e[s] < en[s]) ? e[s] : (en[s] - 8u);
            ec = (ec > e[s]) ? e[s] : ec;
            idx[s] = colp[ec + g];
        }

        while (e[0] < en[0] || e[1] < en[1] || e[2] < en[2] || e[3] < en[3]) {
            float msk[4];
            h8 v[4];
            #pragma unroll
            for (int s = 0; s < 4; ++s) msk[s] = (e[s] < en[s]) ? 1.f : 0.f;
            #pragma unroll
            for (int s = 0; s < 4; ++s) v[s] = *(const h8*)(hp + (size_t)idx[s] * HS2_LD + c * 8);
            #pragma unroll
            for (int s = 0; s < 4; ++s) {
                e[s] += 8;
                unsigned ec = (e[s] < en[s]) ? e[s] : (en[s] - 8u);
                ec = (ec > e[s]) ? e[s] : ec;
                idx[s] = colp[ec + g];
            }
            #pragma unroll
            for (int s = 0; s < 4; ++s)
                #pragma unroll
                for (int j = 0; j < 8; ++j) acc[s][j] += (float)v[s][j] * msk[s];
        }

        #pragma unroll
        for (int off = 8; off <= 32; off <<= 1)
            #pragma unroll
            for (int s = 0; s < 4; ++s)
                #pragma unroll
                for (int j = 0; j < 8; ++j) acc[s][j] += __shfl_xor(acc[s][j], off, 64);

        if (g == 0) {
            #pragma unroll
            for (int s = 0; s < 4; ++s) {
                int nd = n0 + s;
                if (nd < N) {
                    float din = dinv[nd];
                    #pragma unroll
                    for (int j = 0; j < 8; ++j) { acc[s][j] *= din; csum[j] += acc[s][j]; }
                    if (c < 5) {
                        *(float4*)(out + (size_t)nd * F_OUT + c * 8) =
                            make_float4(acc[s][0], acc[s][1], acc[s][2], acc[s][3]);
                        *(float4*)(out + (size_t)nd * F_OUT + c * 8 + 4) =
                            make_float4(acc[s][4], acc[s][5], acc[s][6], acc[s][7]);
                    }
                }
            }
        }
    }

    if (g == 0) {
        #pragma unroll
        for (int j = 0; j < 8; ++j) part[wv][c][j] = csum[j];
    }
    __syncthreads();
    int tid = threadIdx.x;
    if (tid < F_OUT) {
        int cc = tid >> 3, jj = tid & 7;
        float s = part[0][cc][jj] + part[1][cc][jj] + part[2][cc][jj] + part[3][cc][jj];
        atomicAdd(&colsum[tid], s);
    }
}

// ---------------------------------------------------------------- PairNorm-SI + log_softmax
__global__ __launch_bounds__(128) void k_final(float* __restrict__ out,
                                               const float* __restrict__ colsum, int N) {
    __shared__ float sMean[F_OUT];
    if (threadIdx.x < F_OUT) sMean[threadIdx.x] = colsum[threadIdx.x] * (1.0f / (float)N);
    __syncthreads();
    int n = blockIdx.x * blockDim.x + threadIdx.x;
    if (n >= N) return;
    float* row = out + (size_t)n * F_OUT;
    float v[F_OUT];
    float ss = 0.f;
    #pragma unroll
    for (int f = 0; f < F_OUT; ++f) {
        float t = row[f] - sMean[f];
        v[f] = t;
        ss += t * t;
    }
    float scale = 1.0f / sqrtf(ss + 1e-6f);
    float m = -1e30f;
    #pragma unroll
    for (int f = 0; f < F_OUT; ++f) {
        float y = v[f] * scale;
        v[f] = y;
        m = fmaxf(m, y);
    }
    float sum = 0.f;
    #pragma unroll
    for (int f = 0; f < F_OUT; ++f) sum += expf(v[f] - m);
    float lse = logf(sum);
    #pragma unroll
    for (int f = 0; f < F_OUT; ++f) row[f] = v[f] - m - lse;
}

extern "C" void kernel_launch(void* const* d_in, const int* in_sizes, int n_in,
                              void* d_out, int out_size, void* d_ws, size_t ws_size,
                              hipStream_t stream) {
    const float* x  = (const float*)d_in[0];
    const int*   ei = (const int*)d_in[1];   // int32 per harness (verified R1)
    const float* W1 = (const float*)d_in[2];
    const float* b1 = (const float*)d_in[3];
    const float* W2 = (const float*)d_in[4];
    // b2 unused: cancels under PairNorm mean subtraction.
    float* out = (float*)d_out;

    int N = in_sizes[0] / F_IN;
    int E = in_sizes[1] / 2;
    const int* src = ei;
    const int* dst = ei + E;

    // byte layout with 128B alignment per region.
    // memset zone: degc + aggf + ticket (must precede everything else).
    char* p = (char*)d_ws;
    auto alloc = [&](size_t bytes) { char* r = p; p += (bytes + 127) & ~(size_t)127; return r; };
    unsigned* degc   = (unsigned*)alloc((size_t)N * 4);
    unsigned* aggf   = (unsigned*)alloc(512 * 4);
    unsigned* ticket = (unsigned*)alloc(4);
    char* zend = p;  // end of memset zone
    unsigned* cursor = (unsigned*)alloc((size_t)N * 4);
    float*    colsum = (float*)   alloc(64 * 4);
    unsigned* rowptr = (unsigned*)alloc((size_t)(N + 1) * 4);
    unsigned* colp   = (unsigned*)alloc((size_t)(E + 8 * N + 8) * 4);
    float*    dinv   = (float*)   alloc((size_t)(N + 1) * 4);
    __half*   agg1h  = (__half*)  alloc((size_t)64 * (N + 1) * 2);
    __half*   hs1    = (__half*)  alloc((size_t)64 * (N + 1) * 2);
    __half*   hs2    = (__half*)  alloc((size_t)64 * (N + 1) * 2);
    __half*   Wt     = (__half*)  alloc((size_t)16384 * 2);
    __half*   W2t    = (__half*)  alloc((size_t)4096 * 2);

    hipMemsetAsync(d_ws, 0, (size_t)(zend - (char*)d_ws), stream);

    int nA = (N + 255) / 256;  // 391 for N=100000 (<512 aggf slots)
    k_degw<<<(E + 20480 + 255) / 256, 256, 0, stream>>>(dst, degc, E, W1, W2, Wt, W2t);
    k_scan<<<nA, 256, 0, stream>>>(degc, aggf, ticket, rowptr, dinv, cursor, colsum, N);
    k_fillpad<<<2048, 256, 0, stream>>>(src, dst, degc, rowptr, cursor, colp, E, N);
    k_mm1<<<(N + 63) / 64, 256, 0, stream>>>(x, Wt, dinv, hs1, N);
    int nodes4 = (N + 3) / 4;                       // waves needed (4 nodes/wave)
    k_agg1<<<(nodes4 + 3) / 4, 256, 0, stream>>>(rowptr, colp, dinv, hs1, b1, agg1h, N);
    k_mm2<<<(N + 64) / 64, 256, 0, stream>>>(agg1h, W2t, dinv, hs2, N);
    k_agg2<<<2048, 256, 0, stream>>>(rowptr, colp, dinv, hs2, out, colsum, N);
    k_final<<<(N + 127) / 128, 128, 0, stream>>>(out, colsum, N);
}